// Round 2
// baseline (539.593 us; speedup 1.0000x reference)
//
#include <hip/hip_runtime.h>

typedef __bf16 bf16x8 __attribute__((ext_vector_type(8)));
typedef float f32x4 __attribute__((ext_vector_type(4)));

#define MFMA16(a, b, c) __builtin_amdgcn_mfma_f32_16x16x32_bf16(a, b, c, 0, 0, 0)
#define LOG2E 1.44269504088896340736f

__device__ __forceinline__ unsigned short f2bf(float f) {
  union { float f; unsigned u; } v; v.f = f;
  return (unsigned short)((v.u + 0x7fffu + ((v.u >> 16) & 1u)) >> 16);
}
__device__ __forceinline__ bf16x8 ld_frag(const unsigned short* p) {
  return *(const bf16x8*)p;  // 16B-aligned by construction
}
__device__ __forceinline__ void gld_lds16(const unsigned short* g, unsigned short* l) {
  __builtin_amdgcn_global_load_lds(
      (const __attribute__((address_space(1))) unsigned int*)(const void*)g,
      (__attribute__((address_space(3))) unsigned int*)(void*)l, 16, 0, 0);
}

// fp32 -> bf16, 4 elements/thread
__global__ void cvt_f2bf(const float* __restrict__ in,
                         unsigned short* __restrict__ out, int n4) {
  int i = blockIdx.x * blockDim.x + threadIdx.x;
  if (i < n4) {
    float4 v = ((const float4*)in)[i];
    ushort4 o;
    o.x = f2bf(v.x); o.y = f2bf(v.y); o.z = f2bf(v.z); o.w = f2bf(v.w);
    ((ushort4*)out)[i] = o;
  }
}

// ---------------------------------------------------------------------------
// C[M,N] = A[M,K] * B[N,K]^T + bias[N]   (A,B bf16; bias fp32)
// mode 0: store fp32 to outf[M,N]
// mode 1: QKV split: n<512 -> qbuf[m,n]; n<1024 -> kbuf[m,n-512];
//         else transposed vtbuf[b][n-1024][s]  (m = b*4096 + s), all bf16
// 128x128 tile, BK=32, 256 threads, 4 waves in 2x2, wave tile 64x64.
// ---------------------------------------------------------------------------
__global__ void gemm_bt(const unsigned short* __restrict__ A,
                        const unsigned short* __restrict__ B,
                        const float* __restrict__ bias,
                        float* __restrict__ outf,
                        unsigned short* __restrict__ qbuf,
                        unsigned short* __restrict__ kbuf,
                        unsigned short* __restrict__ vtbuf,
                        int M, int N, int K, int mode) {
  __shared__ alignas(16) unsigned short As[128 * 32];
  __shared__ alignas(16) unsigned short Bs[128 * 32];
  const int n0 = blockIdx.x * 128, m0 = blockIdx.y * 128;
  const int tid = threadIdx.x;
  const int l = tid & 63, w = tid >> 6;
  const int quad = l >> 4, c = l & 15;
  const int wm = (w >> 1) * 64, wn = (w & 1) * 64;

  f32x4 acc[4][4] = {};
  const int kiters = K >> 5;
  for (int kt = 0; kt < kiters; ++kt) {
    __syncthreads();  // protect previous iteration's frag reads
    const int kk = kt * 32 + (l & 3) * 8;
    const int row = l >> 2;  // 0..15 within the 16-row group
#pragma unroll
    for (int i = 0; i < 2; ++i) {
      const int rbase = i * 64 + w * 16;
      gld_lds16(&A[(size_t)(m0 + rbase + row) * K + kk], &As[rbase * 32]);
      gld_lds16(&B[(size_t)(n0 + rbase + row) * K + kk], &Bs[rbase * 32]);
    }
    __syncthreads();  // staging complete (vmcnt drain at barrier)
    bf16x8 af[4], bfr[4];
#pragma unroll
    for (int t = 0; t < 4; ++t) {
      af[t] = ld_frag(&As[(wm + t * 16 + c) * 32 + quad * 8]);
      bfr[t] = ld_frag(&Bs[(wn + t * 16 + c) * 32 + quad * 8]);
    }
#pragma unroll
    for (int mt = 0; mt < 4; ++mt)
#pragma unroll
      for (int nt = 0; nt < 4; ++nt)
        acc[mt][nt] = MFMA16(af[mt], bfr[nt], acc[mt][nt]);
  }

  // epilogue: C row = quad*4 + reg, col = c
#pragma unroll
  for (int nt = 0; nt < 4; ++nt) {
    const int n = n0 + wn + nt * 16 + c;
    const float bsum = bias[n];
#pragma unroll
    for (int mt = 0; mt < 4; ++mt) {
      const int mbase = m0 + wm + mt * 16 + quad * 4;
      if (mode == 0) {
#pragma unroll
        for (int r = 0; r < 4; ++r)
          outf[(size_t)(mbase + r) * N + n] = acc[mt][nt][r] + bsum;
      } else if (n < 1024) {
        unsigned short* dst = (n < 512) ? qbuf : kbuf;
        const int nn = n & 511;
#pragma unroll
        for (int r = 0; r < 4; ++r)
          dst[(size_t)(mbase + r) * 512 + nn] = f2bf(acc[mt][nt][r] + bsum);
      } else {
        const int d = n - 1024;
        const int bb = mbase >> 12, s = mbase & 4095;  // 4 consecutive s values
        ushort4 pk;
        pk.x = f2bf(acc[mt][nt][0] + bsum);
        pk.y = f2bf(acc[mt][nt][1] + bsum);
        pk.z = f2bf(acc[mt][nt][2] + bsum);
        pk.w = f2bf(acc[mt][nt][3] + bsum);
        *(ushort4*)&vtbuf[((size_t)bb * 512 + d) * 4096 + s] = pk;
      }
    }
  }
}

// ---------------------------------------------------------------------------
// Flash attention: Q[b,s,d], K[b,s,d], Vt[b,d,s] (bf16) -> O[b,s,d] (bf16),
// scale 0.125. Grid 256 = B(4) * S/64. Block 256 (4 waves); wave owns 16 q-rows.
// KV tile 32, double-buffered LDS; k_lds rows padded (520), v_lds XOR-swizzled.
// ---------------------------------------------------------------------------
#define KROW 520

__global__ __launch_bounds__(256, 1) void attn_kernel(
    const unsigned short* __restrict__ Q, const unsigned short* __restrict__ Kb,
    const unsigned short* __restrict__ Vt, unsigned short* __restrict__ O) {
  __shared__ alignas(16) unsigned short k_lds[2][32 * KROW];
  __shared__ alignas(16) unsigned short v_lds[2][512 * 32];
  __shared__ alignas(16) unsigned short p_lds[4 * 16 * 32];

  const int bid = blockIdx.x;
  const int b = bid >> 6, qt = bid & 63;
  const int s0 = qt * 64;
  const int tid = threadIdx.x;
  const int l = tid & 63, w = tid >> 6;
  const int quad = l >> 4, c = l & 15;
  const size_t boff = (size_t)b * 4096 * 512;

  // Q fragments pinned in registers (A-operand layout: m = c, k = quad*8+j)
  bf16x8 qf[16];
  {
    const unsigned short* qrow = Q + boff + (size_t)(s0 + w * 16 + c) * 512;
#pragma unroll
    for (int ks = 0; ks < 16; ++ks) qf[ks] = ld_frag(&qrow[ks * 32 + quad * 8]);
  }

  f32x4 o[32] = {};
  float m_r[4], l_r[4];
#pragma unroll
  for (int r = 0; r < 4; ++r) { m_r[r] = -1e30f; l_r[r] = 0.f; }

  const unsigned short* Kbase = Kb + boff;
  const unsigned short* Vbase = Vt + (size_t)b * 512 * 4096;

  auto stage = [&](int buf, int kv0) {
#pragma unroll
    for (int i = 0; i < 8; ++i) {  // K: one 1KB row per wave per call
      const int row = i * 4 + w;
      gld_lds16(&Kbase[(size_t)(kv0 + row) * 512 + l * 8], &k_lds[buf][row * KROW]);
    }
#pragma unroll
    for (int i = 0; i < 8; ++i) {  // Vt: 16 d-rows (64B each), XOR-swizzled chunks
      const int dbase = (i * 4 + w) * 16;
      const int d = dbase + (l >> 2);
      const int jl = (l & 3) ^ ((d >> 1) & 3);
      gld_lds16(&Vbase[(size_t)d * 4096 + kv0 + jl * 8], &v_lds[buf][dbase * 32]);
    }
  };

  stage(0, 0);
  for (int it = 0; it < 128; ++it) {
    const int buf = it & 1;
    __syncthreads();  // drains prefetch (vmcnt0) + protects buffer reuse
    if (it + 1 < 128) stage(buf ^ 1, (it + 1) * 32);

    // S = Q K^T  (two 16x16 kv tiles, 2-way split accumulators for ILP)
    f32x4 sa[2][2] = {};
#pragma unroll
    for (int ks = 0; ks < 16; ++ks) {
      const unsigned short* kr = &k_lds[buf][c * KROW + ks * 32 + quad * 8];
      bf16x8 kf0 = ld_frag(kr);
      bf16x8 kf1 = ld_frag(kr + 16 * KROW);
      sa[0][ks & 1] = MFMA16(qf[ks], kf0, sa[0][ks & 1]);
      sa[1][ks & 1] = MFMA16(qf[ks], kf1, sa[1][ks & 1]);
    }
    f32x4 s0v = sa[0][0] + sa[0][1];
    f32x4 s1v = sa[1][0] + sa[1][1];

    // online softmax per row (row = quad*4 + r, cols spread over 16 lanes)
    float alpha[4];
#pragma unroll
    for (int r = 0; r < 4; ++r) {
      const float x0 = s0v[r] * 0.125f, x1 = s1v[r] * 0.125f;
      float v = fmaxf(x0, x1);
      v = fmaxf(v, __shfl_xor(v, 1));
      v = fmaxf(v, __shfl_xor(v, 2));
      v = fmaxf(v, __shfl_xor(v, 4));
      v = fmaxf(v, __shfl_xor(v, 8));
      const float mn = fmaxf(m_r[r], v);
      alpha[r] = exp2f((m_r[r] - mn) * LOG2E);
      m_r[r] = mn;
      const float p0 = exp2f((x0 - mn) * LOG2E);
      const float p1 = exp2f((x1 - mn) * LOG2E);
      p_lds[w * 512 + (quad * 4 + r) * 32 + c] = f2bf(p0);
      p_lds[w * 512 + (quad * 4 + r) * 32 + 16 + c] = f2bf(p1);
      float sm = p0 + p1;
      sm += __shfl_xor(sm, 1);
      sm += __shfl_xor(sm, 2);
      sm += __shfl_xor(sm, 4);
      sm += __shfl_xor(sm, 8);
      l_r[r] = l_r[r] * alpha[r] + sm;
    }
    const f32x4 av = {alpha[0], alpha[1], alpha[2], alpha[3]};
#pragma unroll
    for (int t = 0; t < 32; ++t) o[t] *= av;

    // ensure per-wave p_lds stores are complete before A-layout reload
    asm volatile("s_waitcnt lgkmcnt(0)" ::: "memory");

    // O += P V : P in A-layout from per-wave LDS scratch; Vt frags swizzled
    const bf16x8 pf = ld_frag(&p_lds[w * 512 + c * 32 + quad * 8]);
#pragma unroll
    for (int t = 0; t < 32; ++t) {
      const int d = t * 16 + c;
      const int jp = quad ^ ((d >> 1) & 3);
      bf16x8 vf = ld_frag(&v_lds[buf][d * 32 + jp * 8]);
      o[t] = MFMA16(pf, vf, o[t]);
    }
  }

  float inv[4];
#pragma unroll
  for (int r = 0; r < 4; ++r) inv[r] = 1.0f / l_r[r];
  unsigned short* orow = O + boff;
#pragma unroll
  for (int t = 0; t < 32; ++t)
#pragma unroll
    for (int r = 0; r < 4; ++r)
      orow[(size_t)(s0 + w * 16 + quad * 4 + r) * 512 + t * 16 + c] =
          f2bf(o[t][r] * inv[r]);
}

// ---------------------------------------------------------------------------
extern "C" void kernel_launch(void* const* d_in, const int* in_sizes, int n_in,
                              void* d_out, int out_size, void* d_ws, size_t ws_size,
                              hipStream_t stream) {
  const float* x = (const float*)d_in[0];      // [4,4096,512] fp32
  const float* w_in = (const float*)d_in[1];   // [1536,512] fp32
  const float* b_in = (const float*)d_in[2];   // [1536] fp32
  const float* w_out = (const float*)d_in[3];  // [512,512] fp32
  const float* b_out = (const float*)d_in[4];  // [512] fp32
  float* out = (float*)d_out;                  // [4,4096,512] fp32

  const size_t MTOT = (size_t)4 * 4096 * 512;  // 8,388,608
  unsigned short* q = (unsigned short*)d_ws;
  unsigned short* k = q + MTOT;
  unsigned short* vt = k + MTOT;       // [b][d][s]
  unsigned short* xbf_ao = vt + MTOT;  // x as bf16, later reused as attn out
  unsigned short* w_in_bf = xbf_ao + MTOT;
  unsigned short* w_out_bf = w_in_bf + 1536 * 512;

  // fp32 -> bf16 conversions
  cvt_f2bf<<<dim3((int)(MTOT / 4 / 256)), 256, 0, stream>>>(x, xbf_ao,
                                                            (int)(MTOT / 4));
  cvt_f2bf<<<dim3(768), 256, 0, stream>>>(w_in, w_in_bf, 1536 * 512 / 4);
  cvt_f2bf<<<dim3(256), 256, 0, stream>>>(w_out, w_out_bf, 512 * 512 / 4);

  // qkv = x @ w_in^T + b_in  (V stored transposed)
  gemm_bt<<<dim3(12, 128), 256, 0, stream>>>(xbf_ao, w_in_bf, b_in, nullptr, q,
                                             k, vt, 16384, 1536, 512, 1);
  // flash attention (overwrites xbf_ao with attention output, bf16)
  attn_kernel<<<dim3(256), 256, 0, stream>>>(q, k, vt, xbf_ao);
  // out = ao @ w_out^T + b_out  (fp32 output)
  gemm_bt<<<dim3(4, 128), 256, 0, stream>>>(xbf_ao, w_out_bf, b_out, out,
                                            nullptr, nullptr, nullptr, 16384,
                                            512, 512, 0);
}

// Round 3
// 443.086 us; speedup vs baseline: 1.2178x; 1.2178x over previous
//
#include <hip/hip_runtime.h>

typedef __bf16 bf16x8 __attribute__((ext_vector_type(8)));
typedef float f32x4 __attribute__((ext_vector_type(4)));

#define MFMA16(a, b, c) __builtin_amdgcn_mfma_f32_16x16x32_bf16(a, b, c, 0, 0, 0)
#define LOG2E 1.44269504088896340736f

__device__ __forceinline__ unsigned short f2bf(float f) {
  union { float f; unsigned u; } v; v.f = f;
  return (unsigned short)((v.u + 0x7fffu + ((v.u >> 16) & 1u)) >> 16);
}
__device__ __forceinline__ bf16x8 ld_frag(const unsigned short* p) {
  return *(const bf16x8*)p;  // 16B-aligned by construction
}
__device__ __forceinline__ void gld_lds16(const unsigned short* g, unsigned short* l) {
  __builtin_amdgcn_global_load_lds(
      (const __attribute__((address_space(1))) unsigned int*)(const void*)g,
      (__attribute__((address_space(3))) unsigned int*)(void*)l, 16, 0, 0);
}

// fp32 -> bf16, 4 elements/thread
__global__ void cvt_f2bf(const float* __restrict__ in,
                         unsigned short* __restrict__ out, int n4) {
  int i = blockIdx.x * blockDim.x + threadIdx.x;
  if (i < n4) {
    float4 v = ((const float4*)in)[i];
    ushort4 o;
    o.x = f2bf(v.x); o.y = f2bf(v.y); o.z = f2bf(v.z); o.w = f2bf(v.w);
    ((ushort4*)out)[i] = o;
  }
}

// ---------------------------------------------------------------------------
// C[M,N] = A[M,K] * B[N,K]^T + bias[N]   (A,B bf16; bias fp32)
// mode 0: store fp32 to outf[M,N]
// mode 1: QKV split: n<512 -> qbuf; n<1024 -> kbuf; else transposed vtbuf[b][d][s]
// 128x128 tile, BK=32, 256 threads, 4 waves in 2x2, wave tile 64x64.
// ---------------------------------------------------------------------------
__global__ void gemm_bt(const unsigned short* __restrict__ A,
                        const unsigned short* __restrict__ B,
                        const float* __restrict__ bias,
                        float* __restrict__ outf,
                        unsigned short* __restrict__ qbuf,
                        unsigned short* __restrict__ kbuf,
                        unsigned short* __restrict__ vtbuf,
                        int M, int N, int K, int mode) {
  __shared__ alignas(16) unsigned short As[128 * 32];
  __shared__ alignas(16) unsigned short Bs[128 * 32];
  const int n0 = blockIdx.x * 128, m0 = blockIdx.y * 128;
  const int tid = threadIdx.x;
  const int l = tid & 63, w = tid >> 6;
  const int quad = l >> 4, c = l & 15;
  const int wm = (w >> 1) * 64, wn = (w & 1) * 64;

  f32x4 acc[4][4] = {};
  const int kiters = K >> 5;
  for (int kt = 0; kt < kiters; ++kt) {
    __syncthreads();
    const int kk = kt * 32 + (l & 3) * 8;
    const int row = l >> 2;
#pragma unroll
    for (int i = 0; i < 2; ++i) {
      const int rbase = i * 64 + w * 16;
      gld_lds16(&A[(size_t)(m0 + rbase + row) * K + kk], &As[rbase * 32]);
      gld_lds16(&B[(size_t)(n0 + rbase + row) * K + kk], &Bs[rbase * 32]);
    }
    __syncthreads();
    bf16x8 af[4], bfr[4];
#pragma unroll
    for (int t = 0; t < 4; ++t) {
      af[t] = ld_frag(&As[(wm + t * 16 + c) * 32 + quad * 8]);
      bfr[t] = ld_frag(&Bs[(wn + t * 16 + c) * 32 + quad * 8]);
    }
#pragma unroll
    for (int mt = 0; mt < 4; ++mt)
#pragma unroll
      for (int nt = 0; nt < 4; ++nt)
        acc[mt][nt] = MFMA16(af[mt], bfr[nt], acc[mt][nt]);
  }

#pragma unroll
  for (int nt = 0; nt < 4; ++nt) {
    const int n = n0 + wn + nt * 16 + c;
    const float bsum = bias[n];
#pragma unroll
    for (int mt = 0; mt < 4; ++mt) {
      const int mbase = m0 + wm + mt * 16 + quad * 4;
      if (mode == 0) {
#pragma unroll
        for (int r = 0; r < 4; ++r)
          outf[(size_t)(mbase + r) * N + n] = acc[mt][nt][r] + bsum;
      } else if (n < 1024) {
        unsigned short* dst = (n < 512) ? qbuf : kbuf;
        const int nn = n & 511;
#pragma unroll
        for (int r = 0; r < 4; ++r)
          dst[(size_t)(mbase + r) * 512 + nn] = f2bf(acc[mt][nt][r] + bsum);
      } else {
        const int d = n - 1024;
        const int bb = mbase >> 12, s = mbase & 4095;
        ushort4 pk;
        pk.x = f2bf(acc[mt][nt][0] + bsum);
        pk.y = f2bf(acc[mt][nt][1] + bsum);
        pk.z = f2bf(acc[mt][nt][2] + bsum);
        pk.w = f2bf(acc[mt][nt][3] + bsum);
        *(ushort4*)&vtbuf[((size_t)bb * 512 + d) * 4096 + s] = pk;
      }
    }
  }
}

// ---------------------------------------------------------------------------
// Flash attention, transposed-S formulation:
//   S^T = K Q^T (C-layout: row=kv, col=q)  -> softmax reduction is in-lane
//   O^T = V^T P^T (C-layout: row=d, col=q)
// Q[b,s,d], K[b,s,d], Vt[b,d,s] (bf16) -> O[b,s,d] (bf16), scale 0.125.
// Grid 256 = B(4)*S/64, XCD-swizzled (batch pinned to an XCD pair for L2).
// Block 256 (4 waves); wave owns 16 q-rows. KV tile 32, double-buffered LDS.
// ---------------------------------------------------------------------------
#define KROW 520
#define PROW 40

__global__ __launch_bounds__(256, 1) void attn_kernel(
    const unsigned short* __restrict__ Q, const unsigned short* __restrict__ Kb,
    const unsigned short* __restrict__ Vt, unsigned short* __restrict__ O) {
  __shared__ alignas(16) unsigned short k_lds[2][32 * KROW];
  __shared__ alignas(16) unsigned short v_lds[2][512 * 32];
  __shared__ alignas(16) unsigned short p_lds[4 * 16 * PROW];

  const int bid = blockIdx.x;
  const int xcd = bid & 7;
  const int b = xcd >> 1;                         // 2 XCDs per batch
  const int qt = (bid >> 3) | ((xcd & 1) << 5);   // 0..63
  const int s0 = qt * 64;
  const int tid = threadIdx.x;
  const int l = tid & 63, w = tid >> 6;
  const int quad = l >> 4, c = l & 15;
  const size_t boff = (size_t)b * 4096 * 512;

  // Q fragments pinned (A/B-operand layout: idx = c, k = quad*8+j)
  bf16x8 qf[16];
  {
    const unsigned short* qrow = Q + boff + (size_t)(s0 + w * 16 + c) * 512;
#pragma unroll
    for (int ks = 0; ks < 16; ++ks) qf[ks] = ld_frag(&qrow[ks * 32 + quad * 8]);
  }

  f32x4 o[32] = {};           // O^T: [d = t*16 + quad*4 + r][q = c]
  float m_run = -1e30f, l_run = 0.f;  // per-lane (q = c), replicated across quads

  const unsigned short* Kbase = Kb + boff;
  const unsigned short* Vbase = Vt + (size_t)b * 512 * 4096;

  auto stage = [&](int buf, int kv0) {
#pragma unroll
    for (int i = 0; i < 8; ++i) {  // K: one 1KB row per wave per call
      const int row = i * 4 + w;
      gld_lds16(&Kbase[(size_t)(kv0 + row) * 512 + l * 8], &k_lds[buf][row * KROW]);
    }
#pragma unroll
    for (int i = 0; i < 8; ++i) {  // Vt: XOR-swizzled kv-chunks
      const int dbase = (i * 4 + w) * 16;
      const int d = dbase + (l >> 2);
      const int jl = (l & 3) ^ ((d >> 1) & 3);
      gld_lds16(&Vbase[(size_t)d * 4096 + kv0 + jl * 8], &v_lds[buf][dbase * 32]);
    }
  };

  stage(0, 0);
  for (int it = 0; it < 128; ++it) {
    const int buf = it & 1;
    __syncthreads();  // drains prefetch (vmcnt0) + protects buffer reuse
    if (it + 1 < 128) stage(buf ^ 1, (it + 1) * 32);

    // S^T = K Q^T (A = K frag, B = Q frag; identical lane layouts)
    f32x4 sa[2][2] = {};
#pragma unroll
    for (int ks = 0; ks < 16; ++ks) {
      const unsigned short* kr = &k_lds[buf][c * KROW + ks * 32 + quad * 8];
      bf16x8 kf0 = ld_frag(kr);
      bf16x8 kf1 = ld_frag(kr + 16 * KROW);
      sa[0][ks & 1] = MFMA16(kf0, qf[ks], sa[0][ks & 1]);
      sa[1][ks & 1] = MFMA16(kf1, qf[ks], sa[1][ks & 1]);
    }
    const f32x4 s0v = sa[0][0] + sa[0][1];  // kv = quad*4+r (tile0), q = c
    const f32x4 s1v = sa[1][0] + sa[1][1];  // kv = 16+quad*4+r

    // online softmax: 8 kv in-lane, cross-quad via 2 shuffles (raw units;
    // scale*log2e folded into the exp argument)
    const float C1 = 0.125f * LOG2E;
    float m8 = fmaxf(fmaxf(fmaxf(s0v[0], s0v[1]), fmaxf(s0v[2], s0v[3])),
                     fmaxf(fmaxf(s1v[0], s1v[1]), fmaxf(s1v[2], s1v[3])));
    m8 = fmaxf(m8, __shfl_xor(m8, 16));
    m8 = fmaxf(m8, __shfl_xor(m8, 32));
    const float mn = fmaxf(m_run, m8);

    float p0[4], p1[4], s8 = 0.f;
#pragma unroll
    for (int r = 0; r < 4; ++r) {
      p0[r] = exp2f((s0v[r] - mn) * C1);
      p1[r] = exp2f((s1v[r] - mn) * C1);
      s8 += p0[r] + p1[r];
    }
    // store P^T rows [q=c][kv] (two ushort4 = 2x ds_write_b64)
    unsigned short* prow = &p_lds[(w * 16 + c) * PROW];
    ushort4 pk0, pk1;
    pk0.x = f2bf(p0[0]); pk0.y = f2bf(p0[1]); pk0.z = f2bf(p0[2]); pk0.w = f2bf(p0[3]);
    pk1.x = f2bf(p1[0]); pk1.y = f2bf(p1[1]); pk1.z = f2bf(p1[2]); pk1.w = f2bf(p1[3]);
    *(ushort4*)&prow[quad * 4] = pk0;
    *(ushort4*)&prow[16 + quad * 4] = pk1;

    s8 += __shfl_xor(s8, 16);
    s8 += __shfl_xor(s8, 32);

    if (__any(mn > m_run)) {
      const float alpha = exp2f((m_run - mn) * C1);
      l_run = l_run * alpha + s8;
      m_run = mn;
#pragma unroll
      for (int t = 0; t < 32; ++t) o[t] *= alpha;
    } else {
      l_run += s8;
    }

    // ensure P^T stores complete before reload
    asm volatile("s_waitcnt lgkmcnt(0)" ::: "memory");

    // O^T += V^T P^T : A = V frag from LDS, B = P frag (per-wave scratch)
    const bf16x8 pf = ld_frag(&p_lds[(w * 16 + c) * PROW + quad * 8]);
#pragma unroll
    for (int t = 0; t < 32; ++t) {
      const int d = t * 16 + c;
      const int jp = quad ^ ((d >> 1) & 3);
      bf16x8 vf = ld_frag(&v_lds[buf][d * 32 + jp * 8]);
      o[t] = MFMA16(vf, pf, o[t]);
    }
  }

  // epilogue: O^T reg (t, r) -> O[s0 + w*16 + c][t*16 + quad*4 + r]
  const float inv = 1.0f / l_run;
  unsigned short* orow = O + boff + (size_t)(s0 + w * 16 + c) * 512;
#pragma unroll
  for (int t = 0; t < 32; ++t) {
    ushort4 pk;
    pk.x = f2bf(o[t][0] * inv);
    pk.y = f2bf(o[t][1] * inv);
    pk.z = f2bf(o[t][2] * inv);
    pk.w = f2bf(o[t][3] * inv);
    *(ushort4*)&orow[t * 16 + quad * 4] = pk;
  }
}

// ---------------------------------------------------------------------------
extern "C" void kernel_launch(void* const* d_in, const int* in_sizes, int n_in,
                              void* d_out, int out_size, void* d_ws, size_t ws_size,
                              hipStream_t stream) {
  const float* x = (const float*)d_in[0];      // [4,4096,512] fp32
  const float* w_in = (const float*)d_in[1];   // [1536,512] fp32
  const float* b_in = (const float*)d_in[2];   // [1536] fp32
  const float* w_out = (const float*)d_in[3];  // [512,512] fp32
  const float* b_out = (const float*)d_in[4];  // [512] fp32
  float* out = (float*)d_out;                  // [4,4096,512] fp32

  const size_t MTOT = (size_t)4 * 4096 * 512;  // 8,388,608
  unsigned short* q = (unsigned short*)d_ws;
  unsigned short* k = q + MTOT;
  unsigned short* vt = k + MTOT;       // [b][d][s]
  unsigned short* xbf_ao = vt + MTOT;  // x as bf16, later reused as attn out
  unsigned short* w_in_bf = xbf_ao + MTOT;
  unsigned short* w_out_bf = w_in_bf + 1536 * 512;

  cvt_f2bf<<<dim3((int)(MTOT / 4 / 256)), 256, 0, stream>>>(x, xbf_ao,
                                                            (int)(MTOT / 4));
  cvt_f2bf<<<dim3(768), 256, 0, stream>>>(w_in, w_in_bf, 1536 * 512 / 4);
  cvt_f2bf<<<dim3(256), 256, 0, stream>>>(w_out, w_out_bf, 512 * 512 / 4);

  gemm_bt<<<dim3(12, 128), 256, 0, stream>>>(xbf_ao, w_in_bf, b_in, nullptr, q,
                                             k, vt, 16384, 1536, 512, 1);
  attn_kernel<<<dim3(256), 256, 0, stream>>>(q, k, vt, xbf_ao);
  gemm_bt<<<dim3(4, 128), 256, 0, stream>>>(xbf_ao, w_out_bf, b_out, out,
                                            nullptr, nullptr, nullptr, 16384,
                                            512, 512, 0);
}

// Round 4
// 432.297 us; speedup vs baseline: 1.2482x; 1.0250x over previous
//
#include <hip/hip_runtime.h>

typedef __bf16 bf16x8 __attribute__((ext_vector_type(8)));
typedef float f32x4 __attribute__((ext_vector_type(4)));

#define MFMA16(a, b, c) __builtin_amdgcn_mfma_f32_16x16x32_bf16(a, b, c, 0, 0, 0)
#define LOG2E 1.44269504088896340736f

__device__ __forceinline__ unsigned short f2bf(float f) {
  union { float f; unsigned u; } v; v.f = f;
  return (unsigned short)((v.u + 0x7fffu + ((v.u >> 16) & 1u)) >> 16);
}
__device__ __forceinline__ bf16x8 ld_frag(const unsigned short* p) {
  return *(const bf16x8*)p;  // 16B-aligned by construction
}
__device__ __forceinline__ void gld_lds16(const unsigned short* g, unsigned short* l) {
  __builtin_amdgcn_global_load_lds(
      (const __attribute__((address_space(1))) unsigned int*)(const void*)g,
      (__attribute__((address_space(3))) unsigned int*)(void*)l, 16, 0, 0);
}

// fp32 -> bf16, 4 elements/thread
__global__ void cvt_f2bf(const float* __restrict__ in,
                         unsigned short* __restrict__ out, int n4) {
  int i = blockIdx.x * blockDim.x + threadIdx.x;
  if (i < n4) {
    float4 v = ((const float4*)in)[i];
    ushort4 o;
    o.x = f2bf(v.x); o.y = f2bf(v.y); o.z = f2bf(v.z); o.w = f2bf(v.w);
    ((ushort4*)out)[i] = o;
  }
}

// ---------------------------------------------------------------------------
// C[M,N] = A[M,K] * B[N,K]^T + bias[N]   (A,B bf16; bias fp32)
// mode 0: store fp32 to outf[M,N]
// mode 1: QKV split: n<512 -> qbuf; n<1024 -> kbuf; else transposed vtbuf[b][d][s]
// 128x128 tile, BK=32, 256 threads, 4 waves in 2x2, wave tile 64x64.
// ---------------------------------------------------------------------------
__global__ void gemm_bt(const unsigned short* __restrict__ A,
                        const unsigned short* __restrict__ B,
                        const float* __restrict__ bias,
                        float* __restrict__ outf,
                        unsigned short* __restrict__ qbuf,
                        unsigned short* __restrict__ kbuf,
                        unsigned short* __restrict__ vtbuf,
                        int M, int N, int K, int mode) {
  __shared__ alignas(16) unsigned short As[128 * 32];
  __shared__ alignas(16) unsigned short Bs[128 * 32];
  const int n0 = blockIdx.x * 128, m0 = blockIdx.y * 128;
  const int tid = threadIdx.x;
  const int l = tid & 63, w = tid >> 6;
  const int quad = l >> 4, c = l & 15;
  const int wm = (w >> 1) * 64, wn = (w & 1) * 64;

  f32x4 acc[4][4] = {};
  const int kiters = K >> 5;
  for (int kt = 0; kt < kiters; ++kt) {
    __syncthreads();
    const int kk = kt * 32 + (l & 3) * 8;
    const int row = l >> 2;
#pragma unroll
    for (int i = 0; i < 2; ++i) {
      const int rbase = i * 64 + w * 16;
      gld_lds16(&A[(size_t)(m0 + rbase + row) * K + kk], &As[rbase * 32]);
      gld_lds16(&B[(size_t)(n0 + rbase + row) * K + kk], &Bs[rbase * 32]);
    }
    __syncthreads();
    bf16x8 af[4], bfr[4];
#pragma unroll
    for (int t = 0; t < 4; ++t) {
      af[t] = ld_frag(&As[(wm + t * 16 + c) * 32 + quad * 8]);
      bfr[t] = ld_frag(&Bs[(wn + t * 16 + c) * 32 + quad * 8]);
    }
#pragma unroll
    for (int mt = 0; mt < 4; ++mt)
#pragma unroll
      for (int nt = 0; nt < 4; ++nt)
        acc[mt][nt] = MFMA16(af[mt], bfr[nt], acc[mt][nt]);
  }

#pragma unroll
  for (int nt = 0; nt < 4; ++nt) {
    const int n = n0 + wn + nt * 16 + c;
    const float bsum = bias[n];
#pragma unroll
    for (int mt = 0; mt < 4; ++mt) {
      const int mbase = m0 + wm + mt * 16 + quad * 4;
      if (mode == 0) {
#pragma unroll
        for (int r = 0; r < 4; ++r)
          outf[(size_t)(mbase + r) * N + n] = acc[mt][nt][r] + bsum;
      } else if (n < 1024) {
        unsigned short* dst = (n < 512) ? qbuf : kbuf;
        const int nn = n & 511;
#pragma unroll
        for (int r = 0; r < 4; ++r)
          dst[(size_t)(mbase + r) * 512 + nn] = f2bf(acc[mt][nt][r] + bsum);
      } else {
        const int d = n - 1024;
        const int bb = mbase >> 12, s = mbase & 4095;
        ushort4 pk;
        pk.x = f2bf(acc[mt][nt][0] + bsum);
        pk.y = f2bf(acc[mt][nt][1] + bsum);
        pk.z = f2bf(acc[mt][nt][2] + bsum);
        pk.w = f2bf(acc[mt][nt][3] + bsum);
        *(ushort4*)&vtbuf[((size_t)bb * 512 + d) * 4096 + s] = pk;
      }
    }
  }
}

// ---------------------------------------------------------------------------
// Flash attention, transposed-S, kv-split-2:
// Grid 512 = 4b x 64qt x 2 kv-halves; block owns 64 q x 2048 kv (64 iters).
// Single-buffered LDS (~70 KB) -> 2 blocks/CU; cross-block overlap hides the
// staging barrier. Each block writes l-normalized partial O (bf16) + (m,l).
// ---------------------------------------------------------------------------
#define KROW 520
#define PROW 40

__global__ __launch_bounds__(256, 2) void attn_kernel(
    const unsigned short* __restrict__ Q, const unsigned short* __restrict__ Kb,
    const unsigned short* __restrict__ Vt, unsigned short* __restrict__ part0,
    unsigned short* __restrict__ part1, float2* __restrict__ mlbuf) {
  __shared__ alignas(16) unsigned short k_lds[32 * KROW];
  __shared__ alignas(16) unsigned short v_lds[512 * 32];
  __shared__ alignas(16) unsigned short p_lds[4 * 16 * PROW];

  const int bid = blockIdx.x;
  const int xcd = bid & 7;
  const int b = xcd >> 1;                          // 2 XCDs per batch
  const int half = (bid >> 3) & 1;                 // kv half
  const int qt = (bid >> 4) | ((xcd & 1) << 5);    // 0..63
  const int s0 = qt * 64;
  const int kvbase = half * 2048;
  const int tid = threadIdx.x;
  const int l = tid & 63, w = tid >> 6;
  const int quad = l >> 4, c = l & 15;
  const size_t boff = (size_t)b * 4096 * 512;

  // Q fragments pinned (A/B-operand layout: idx = c, k = quad*8+j)
  bf16x8 qf[16];
  {
    const unsigned short* qrow = Q + boff + (size_t)(s0 + w * 16 + c) * 512;
#pragma unroll
    for (int ks = 0; ks < 16; ++ks) qf[ks] = ld_frag(&qrow[ks * 32 + quad * 8]);
  }

  f32x4 o[32] = {};                   // O^T: [d = t*16 + quad*4 + r][q = c]
  float m_run = -1e30f, l_run = 0.f;  // per-lane (q = c), replicated over quads

  const unsigned short* Kbase = Kb + boff;
  const unsigned short* Vbase = Vt + (size_t)b * 512 * 4096;

  auto stage = [&](int kv0) {
#pragma unroll
    for (int i = 0; i < 8; ++i) {  // K: one 1KB row per wave per call
      const int row = i * 4 + w;
      gld_lds16(&Kbase[(size_t)(kv0 + row) * 512 + l * 8], &k_lds[row * KROW]);
    }
#pragma unroll
    for (int i = 0; i < 8; ++i) {  // Vt: XOR-swizzled kv-chunks
      const int dbase = (i * 4 + w) * 16;
      const int d = dbase + (l >> 2);
      const int jl = (l & 3) ^ ((d >> 1) & 3);
      gld_lds16(&Vbase[(size_t)d * 4096 + kv0 + jl * 8], &v_lds[dbase * 32]);
    }
  };

  for (int it = 0; it < 64; ++it) {
    __syncthreads();  // previous iteration's frag reads done -> buffer free
    stage(kvbase + it * 32);
    __syncthreads();  // staging complete (vmcnt drained at barrier)

    // S^T = K Q^T (A = K frag, B = Q frag; identical lane layouts)
    f32x4 sa[2][2] = {};
#pragma unroll
    for (int ks = 0; ks < 16; ++ks) {
      const unsigned short* kr = &k_lds[c * KROW + ks * 32 + quad * 8];
      bf16x8 kf0 = ld_frag(kr);
      bf16x8 kf1 = ld_frag(kr + 16 * KROW);
      sa[0][ks & 1] = MFMA16(kf0, qf[ks], sa[0][ks & 1]);
      sa[1][ks & 1] = MFMA16(kf1, qf[ks], sa[1][ks & 1]);
    }
    const f32x4 s0v = sa[0][0] + sa[0][1];  // kv = quad*4+r, q = c
    const f32x4 s1v = sa[1][0] + sa[1][1];  // kv = 16+quad*4+r

    // online softmax: 8 kv in-lane + 2 cross-quad shuffles
    const float C1 = 0.125f * LOG2E;
    float m8 = fmaxf(fmaxf(fmaxf(s0v[0], s0v[1]), fmaxf(s0v[2], s0v[3])),
                     fmaxf(fmaxf(s1v[0], s1v[1]), fmaxf(s1v[2], s1v[3])));
    m8 = fmaxf(m8, __shfl_xor(m8, 16));
    m8 = fmaxf(m8, __shfl_xor(m8, 32));
    const float mn = fmaxf(m_run, m8);

    float p0[4], p1[4], s8 = 0.f;
#pragma unroll
    for (int r = 0; r < 4; ++r) {
      p0[r] = exp2f((s0v[r] - mn) * C1);
      p1[r] = exp2f((s1v[r] - mn) * C1);
      s8 += p0[r] + p1[r];
    }
    // store P^T rows [q=c][kv] (two ushort4 = 2x ds_write_b64)
    unsigned short* prow = &p_lds[(w * 16 + c) * PROW];
    ushort4 pk0, pk1;
    pk0.x = f2bf(p0[0]); pk0.y = f2bf(p0[1]); pk0.z = f2bf(p0[2]); pk0.w = f2bf(p0[3]);
    pk1.x = f2bf(p1[0]); pk1.y = f2bf(p1[1]); pk1.z = f2bf(p1[2]); pk1.w = f2bf(p1[3]);
    *(ushort4*)&prow[quad * 4] = pk0;
    *(ushort4*)&prow[16 + quad * 4] = pk1;

    s8 += __shfl_xor(s8, 16);
    s8 += __shfl_xor(s8, 32);

    if (__any(mn > m_run)) {
      const float alpha = exp2f((m_run - mn) * C1);
      l_run = l_run * alpha + s8;
      m_run = mn;
#pragma unroll
      for (int t = 0; t < 32; ++t) o[t] *= alpha;
    } else {
      l_run += s8;
    }

    // ensure per-wave P^T stores complete before reload
    asm volatile("s_waitcnt lgkmcnt(0)" ::: "memory");

    // O^T += V^T P^T : A = V frag from LDS, B = P frag (per-wave scratch)
    const bf16x8 pf = ld_frag(&p_lds[(w * 16 + c) * PROW + quad * 8]);
#pragma unroll
    for (int t = 0; t < 32; ++t) {
      const int d = t * 16 + c;
      const int jp = quad ^ ((d >> 1) & 3);
      bf16x8 vf = ld_frag(&v_lds[d * 32 + jp * 8]);
      o[t] = MFMA16(vf, pf, o[t]);
    }
  }

  // epilogue: normalized partial + (m,l) for the merge
  unsigned short* part = half ? part1 : part0;
  const float inv = 1.0f / l_run;
  unsigned short* orow = part + boff + (size_t)(s0 + w * 16 + c) * 512;
#pragma unroll
  for (int t = 0; t < 32; ++t) {
    ushort4 pk;
    pk.x = f2bf(o[t][0] * inv);
    pk.y = f2bf(o[t][1] * inv);
    pk.z = f2bf(o[t][2] * inv);
    pk.w = f2bf(o[t][3] * inv);
    *(ushort4*)&orow[t * 16 + quad * 4] = pk;
  }
  if (quad == 0) {
    float2 ml; ml.x = m_run; ml.y = l_run;
    mlbuf[(size_t)half * 16384 + b * 4096 + s0 + w * 16 + c] = ml;
  }
}

// ---------------------------------------------------------------------------
// Merge the two kv-half streams: out = (w0*P0 + w1*P1), w_h = l_h*2^((m_h-M)*C1)
// 8 elems/thread; writes in place over part0.
// ---------------------------------------------------------------------------
__global__ void merge_halves(const unsigned short* __restrict__ p1,
                             const float2* __restrict__ mlbuf,
                             unsigned short* __restrict__ p0out) {
  const int i = blockIdx.x * blockDim.x + threadIdx.x;  // one per 8 elems
  const int row = i >> 6;                               // 512 d / 8 = 64
  const float2 a = mlbuf[row];
  const float2 bb = mlbuf[16384 + row];
  const float C1 = 0.125f * LOG2E;
  const float M = fmaxf(a.x, bb.x);
  float w0 = a.y * exp2f((a.x - M) * C1);
  float w1 = bb.y * exp2f((bb.x - M) * C1);
  const float inv = 1.0f / (w0 + w1);
  w0 *= inv; w1 *= inv;
  bf16x8 v0 = *(const bf16x8*)(p0out + (size_t)i * 8);
  bf16x8 v1 = *(const bf16x8*)(p1 + (size_t)i * 8);
  ushort4 o0, o1;
  o0.x = f2bf(w0 * (float)v0[0] + w1 * (float)v1[0]);
  o0.y = f2bf(w0 * (float)v0[1] + w1 * (float)v1[1]);
  o0.z = f2bf(w0 * (float)v0[2] + w1 * (float)v1[2]);
  o0.w = f2bf(w0 * (float)v0[3] + w1 * (float)v1[3]);
  o1.x = f2bf(w0 * (float)v0[4] + w1 * (float)v1[4]);
  o1.y = f2bf(w0 * (float)v0[5] + w1 * (float)v1[5]);
  o1.z = f2bf(w0 * (float)v0[6] + w1 * (float)v1[6]);
  o1.w = f2bf(w0 * (float)v0[7] + w1 * (float)v1[7]);
  *(ushort4*)(p0out + (size_t)i * 8) = o0;
  *(ushort4*)(p0out + (size_t)i * 8 + 4) = o1;
}

// ---------------------------------------------------------------------------
extern "C" void kernel_launch(void* const* d_in, const int* in_sizes, int n_in,
                              void* d_out, int out_size, void* d_ws, size_t ws_size,
                              hipStream_t stream) {
  const float* x = (const float*)d_in[0];      // [4,4096,512] fp32
  const float* w_in = (const float*)d_in[1];   // [1536,512] fp32
  const float* b_in = (const float*)d_in[2];   // [1536] fp32
  const float* w_out = (const float*)d_in[3];  // [512,512] fp32
  const float* b_out = (const float*)d_in[4];  // [512] fp32
  float* out = (float*)d_out;                  // [4,4096,512] fp32

  const size_t MTOT = (size_t)4 * 4096 * 512;  // 8,388,608
  unsigned short* q = (unsigned short*)d_ws;
  unsigned short* k = q + MTOT;
  unsigned short* vt = k + MTOT;        // [b][d][s]
  unsigned short* xbf = vt + MTOT;      // x bf16 -> attn part0 -> merged ao
  unsigned short* part1 = xbf + MTOT;   // attn part1
  unsigned short* w_in_bf = part1 + MTOT;
  unsigned short* w_out_bf = w_in_bf + 1536 * 512;
  float2* mlbuf = (float2*)(w_out_bf + 512 * 512);  // 2 x 16384 float2

  cvt_f2bf<<<dim3((int)(MTOT / 4 / 256)), 256, 0, stream>>>(x, xbf,
                                                            (int)(MTOT / 4));
  cvt_f2bf<<<dim3(768), 256, 0, stream>>>(w_in, w_in_bf, 1536 * 512 / 4);
  cvt_f2bf<<<dim3(256), 256, 0, stream>>>(w_out, w_out_bf, 512 * 512 / 4);

  gemm_bt<<<dim3(12, 128), 256, 0, stream>>>(xbf, w_in_bf, b_in, nullptr, q, k,
                                             vt, 16384, 1536, 512, 1);
  // flash attention, kv-split-2 (part0 overwrites xbf; x is dead)
  attn_kernel<<<dim3(512), 256, 0, stream>>>(q, k, vt, xbf, part1, mlbuf);
  // merge halves in place into xbf
  merge_halves<<<dim3(4096), 256, 0, stream>>>(part1, mlbuf, xbf);
  // out = ao @ w_out^T + b_out  (fp32 output)
  gemm_bt<<<dim3(4, 128), 256, 0, stream>>>(xbf, w_out_bf, b_out, out, nullptr,
                                            nullptr, nullptr, 16384, 512, 512,
                                            0);
}